// Round 2
// baseline (680.286 us; speedup 1.0000x reference)
//
#include <hip/hip_runtime.h>
#include <hip/hip_bf16.h>
#include <stdint.h>

#define SEQ   2048
#define DM    512
#define NH    8
#define DH    64
#define BHN   32        // B*H
#define MR    8192      // B*SEQ
#define NITER 10
#define SCALE_LOG2E 0.18033688011112042f   // (1/8) * log2(e)
#define BETA  0.5f

typedef unsigned short u16;
typedef unsigned char  u8;
typedef long i64;  // 64-bit on amdgcn
typedef __attribute__((ext_vector_type(8))) short bf16x8;
typedef __attribute__((ext_vector_type(4))) float f32x4;

__device__ __forceinline__ u16 f2bf(float f) {
  union { float f; uint32_t u; } v; v.f = f;
  uint32_t r = v.u + 0x7FFFu + ((v.u >> 16) & 1u);
  return (u16)(r >> 16);
}
__device__ __forceinline__ float bf2f(u16 h) {
  union { uint32_t u; float f; } v; v.u = ((uint32_t)h) << 16;
  return v.f;
}
__device__ __forceinline__ void g2l16(const void* g, void* l) {
  __builtin_amdgcn_global_load_lds(
      (const __attribute__((address_space(1))) void*)g,
      (__attribute__((address_space(3))) void*)l, 16, 0, 0);
}
__device__ __forceinline__ uint32_t pk4_fp8(float a, float b, float c, float d) {
  int w = 0;
  w = __builtin_amdgcn_cvt_pk_fp8_f32(a, b, w, false);  // bytes 0,1
  w = __builtin_amdgcn_cvt_pk_fp8_f32(c, d, w, true);   // bytes 2,3
  return (uint32_t)w;
}
__device__ __forceinline__ u8 f2fp8(float a) {
  return (u8)(__builtin_amdgcn_cvt_pk_fp8_f32(a, a, 0, false) & 0xFF);
}

// ---------------- diagnostic: fill out with 1e6 (ws too small) ----------------
__global__ __launch_bounds__(256) void k_diag(float* __restrict__ out, int n) {
  int i = blockIdx.x * 256 + threadIdx.x;
  if (i < n) out[i] = 1.0e6f;
}

// ---------------- fp32 -> bf16 bulk convert (n4 = n/4) ----------------
__global__ __launch_bounds__(256) void k_cvt(const float* __restrict__ s,
                                             u16* __restrict__ d, int n4) {
  int i = blockIdx.x * 256 + threadIdx.x;
  if (i >= n4) return;
  float4 v = reinterpret_cast<const float4*>(s)[i];
  short4 o;
  o.x = (short)f2bf(v.x); o.y = (short)f2bf(v.y);
  o.z = (short)f2bf(v.z); o.w = (short)f2bf(v.w);
  reinterpret_cast<short4*>(d)[i] = o;
}

// ---------------- generic 128x128x32 bf16 GEMM, C = A * B^T ----------------
// MODE 0: out = bf16 [b][h][s][d]            (Q/K projection)
// MODE 1: out = bf16 [bh][d][s], out2 = fp8   (V projection, transposed)
// MODE 2: out = fp32 [m][n] + bias            (output projection)
template <int MODE>
__global__ __launch_bounds__(256, 2) void k_gemm_bt(
    const u16* __restrict__ A, const u16* __restrict__ Bt,
    void* __restrict__ out, void* __restrict__ out2,
    const float* __restrict__ bias, int K, int lda, int ldb, int N) {
  __shared__ __align__(16) u16 lsA[4][128][8];
  __shared__ __align__(16) u16 lsB[4][128][8];
  const int t = threadIdx.x;
  const int mbase = blockIdx.y * 128, nbase = blockIdx.x * 128;
  const int w = t >> 6, l = t & 63;
  const int wr = w >> 1, wc = w & 1;
  const int lr = l & 15, lg = l >> 4;
  f32x4 acc[4][4] = {};
  for (int k0 = 0; k0 < K; k0 += 32) {
#pragma unroll
    for (int i = 0; i < 2; ++i) {
      int idx = t + i * 256;
      int c = idx >> 7, row = idx & 127;
      g2l16(A  + (size_t)(mbase + row) * lda + k0 + c * 8, &lsA[c][row][0]);
      g2l16(Bt + (size_t)(nbase + row) * ldb + k0 + c * 8, &lsB[c][row][0]);
    }
    __syncthreads();
    bf16x8 af[4], bg[4];
#pragma unroll
    for (int f = 0; f < 4; ++f) {
      af[f] = *reinterpret_cast<const bf16x8*>(&lsA[lg][wr * 64 + f * 16 + lr][0]);
      bg[f] = *reinterpret_cast<const bf16x8*>(&lsB[lg][wc * 64 + f * 16 + lr][0]);
    }
#pragma unroll
    for (int mf = 0; mf < 4; ++mf)
#pragma unroll
      for (int nf = 0; nf < 4; ++nf)
        acc[mf][nf] = __builtin_amdgcn_mfma_f32_16x16x32_bf16(af[mf], bg[nf], acc[mf][nf], 0, 0, 0);
    __syncthreads();
  }
#pragma unroll
  for (int mf = 0; mf < 4; ++mf) {
#pragma unroll
    for (int nf = 0; nf < 4; ++nf) {
      const int m0 = mbase + wr * 64 + mf * 16 + lg * 4;
      const int n  = nbase + wc * 64 + nf * 16 + lr;
      if (MODE == 0) {
        int h = n >> 6, d = n & 63;
#pragma unroll
        for (int j = 0; j < 4; ++j) {
          int m = m0 + j, b = m >> 11, s = m & 2047;
          ((u16*)out)[((((size_t)b * NH + h) * SEQ + s) << 6) + d] = f2bf(acc[mf][nf][j]);
        }
      } else if (MODE == 1) {
        int h = n >> 6, d = n & 63;
        int b = m0 >> 11, s0 = m0 & 2047;
        size_t base = (((size_t)b * NH + h) * DH + d) * SEQ + s0;
        short4 pk;
        pk.x = (short)f2bf(acc[mf][nf][0]); pk.y = (short)f2bf(acc[mf][nf][1]);
        pk.z = (short)f2bf(acc[mf][nf][2]); pk.w = (short)f2bf(acc[mf][nf][3]);
        *reinterpret_cast<short4*>(&((u16*)out)[base]) = pk;
        *reinterpret_cast<uint32_t*>(&((u8*)out2)[base]) =
            pk4_fp8(acc[mf][nf][0], acc[mf][nf][1], acc[mf][nf][2], acc[mf][nf][3]);
      } else {
        float bv = bias[n];
#pragma unroll
        for (int j = 0; j < 4; ++j)
          ((float*)out)[(size_t)(m0 + j) * N + n] = acc[mf][nf][j] + bv;
      }
    }
  }
}

// ------- per-head scores: E(fp8) = exp(scale * Q K^T), Dsum += rowsums -------
__global__ __launch_bounds__(256, 2) void k_scores(
    const u16* __restrict__ Q, const u16* __restrict__ Kh,
    u8* __restrict__ E, float* __restrict__ Dsum) {
  __shared__ __align__(16) u16 lsA[4][128][8];
  __shared__ __align__(16) u16 lsB[4][128][8];
  const int t = threadIdx.x;
  const int head = blockIdx.z;
  const int mbase = blockIdx.y * 128, nbase = blockIdx.x * 128;
  const int w = t >> 6, l = t & 63;
  const int wr = w >> 1, wc = w & 1;
  const int lr = l & 15, lg = l >> 4;
  const u16* Aq = Q  + (size_t)head * SEQ * DH;
  const u16* Bk = Kh + (size_t)head * SEQ * DH;
  f32x4 acc[4][4] = {};
  for (int k0 = 0; k0 < DH; k0 += 32) {
#pragma unroll
    for (int i = 0; i < 2; ++i) {
      int idx = t + i * 256;
      int c = idx >> 7, row = idx & 127;
      g2l16(Aq + (size_t)(mbase + row) * DH + k0 + c * 8, &lsA[c][row][0]);
      g2l16(Bk + (size_t)(nbase + row) * DH + k0 + c * 8, &lsB[c][row][0]);
    }
    __syncthreads();
    bf16x8 af[4], bg[4];
#pragma unroll
    for (int f = 0; f < 4; ++f) {
      af[f] = *reinterpret_cast<const bf16x8*>(&lsA[lg][wr * 64 + f * 16 + lr][0]);
      bg[f] = *reinterpret_cast<const bf16x8*>(&lsB[lg][wc * 64 + f * 16 + lr][0]);
    }
#pragma unroll
    for (int mf = 0; mf < 4; ++mf)
#pragma unroll
      for (int nf = 0; nf < 4; ++nf)
        acc[mf][nf] = __builtin_amdgcn_mfma_f32_16x16x32_bf16(af[mf], bg[nf], acc[mf][nf], 0, 0, 0);
    __syncthreads();
  }
  u8* Eh = E + (size_t)head * SEQ * SEQ;
  float rs[4][4];
#pragma unroll
  for (int mf = 0; mf < 4; ++mf)
#pragma unroll
    for (int j = 0; j < 4; ++j) rs[mf][j] = 0.f;
#pragma unroll
  for (int mf = 0; mf < 4; ++mf) {
#pragma unroll
    for (int nf = 0; nf < 4; ++nf) {
      const int m0 = mbase + wr * 64 + mf * 16 + lg * 4;
      const int n  = nbase + wc * 64 + nf * 16 + lr;
#pragma unroll
      for (int j = 0; j < 4; ++j) {
        float e = exp2f(acc[mf][nf][j] * SCALE_LOG2E);
        Eh[(size_t)(m0 + j) * SEQ + n] = f2fp8(e);
        rs[mf][j] += e;
      }
    }
  }
#pragma unroll
  for (int mask = 1; mask <= 8; mask <<= 1)
#pragma unroll
    for (int mf = 0; mf < 4; ++mf)
#pragma unroll
      for (int j = 0; j < 4; ++j) rs[mf][j] += __shfl_xor(rs[mf][j], mask, 64);
  if (lr == 0) {
#pragma unroll
    for (int mf = 0; mf < 4; ++mf)
#pragma unroll
      for (int j = 0; j < 4; ++j)
        atomicAdd(&Dsum[head * SEQ + mbase + wr * 64 + mf * 16 + lg * 4 + j], rs[mf][j]);
  }
}

// ---------------- Fac = beta / Dsum ----------------
__global__ __launch_bounds__(256) void k_fac(const float* __restrict__ Dsum,
                                             float* __restrict__ Fac, int n) {
  int i = blockIdx.x * 256 + threadIdx.x;
  if (i < n) Fac[i] = BETA / Dsum[i];
}

// ------ Horner step (fp8): r_out = V + Fac[m] * (E @ r_in) ------
// E: [bh][s][s] fp8; rin8/rout8: [bh][d=64][s] fp8; VT: [bh][d][s] bf16
// attn (bf16 [b][s][512]) written when writeAttn.
__global__ __launch_bounds__(256, 2) void k_horner8(
    const u8* __restrict__ E, const u8* __restrict__ rin8,
    const u16* __restrict__ VT, const float* __restrict__ Fac,
    u8* __restrict__ rout8, u16* __restrict__ attn, int writeAttn) {
  __shared__ __align__(16) u8 lsA[4][128][16];  // 64 k-vals x 128 rows
  __shared__ __align__(16) u8 lsB[4][64][16];   // 64 k-vals x 64 d
  const int t = threadIdx.x;
  const int head = blockIdx.y;
  const int mbase = blockIdx.x * 128;
  const int w = t >> 6, l = t & 63;
  const int lr = l & 15, lg = l >> 4;
  const u8* Eh = E + (size_t)head * SEQ * SEQ;
  const u8* Rh = rin8 + (size_t)head * DH * SEQ;
  f32x4 acc[2][4] = {};
  for (int k0 = 0; k0 < SEQ; k0 += 64) {
#pragma unroll
    for (int i = 0; i < 2; ++i) {
      int idx = t + i * 256;
      int kc = idx >> 7, row = idx & 127;
      g2l16(Eh + (size_t)(mbase + row) * SEQ + k0 + kc * 16, &lsA[kc][row][0]);
    }
    {
      int kc = t >> 6, dr = t & 63;
      g2l16(Rh + (size_t)dr * SEQ + k0 + kc * 16, &lsB[kc][dr][0]);
    }
    __syncthreads();
#pragma unroll
    for (int ks = 0; ks < 2; ++ks) {
      const int kc = ks * 2 + (lg >> 1), boff = (lg & 1) * 8;
      i64 af[2], bg[4];
#pragma unroll
      for (int mf = 0; mf < 2; ++mf)
        af[mf] = *reinterpret_cast<const i64*>(&lsA[kc][w * 32 + mf * 16 + lr][boff]);
#pragma unroll
      for (int nf = 0; nf < 4; ++nf)
        bg[nf] = *reinterpret_cast<const i64*>(&lsB[kc][nf * 16 + lr][boff]);
#pragma unroll
      for (int mf = 0; mf < 2; ++mf)
#pragma unroll
        for (int nf = 0; nf < 4; ++nf)
          acc[mf][nf] = __builtin_amdgcn_mfma_f32_16x16x32_fp8_fp8(af[mf], bg[nf], acc[mf][nf], 0, 0, 0);
    }
    __syncthreads();
  }
  const u16* VTh = VT + (size_t)head * DH * SEQ;
  const float* Fh = Fac + head * SEQ;
  u8* Ro8 = rout8 + (size_t)head * DH * SEQ;
  const int b = head >> 3, hh = head & 7;
#pragma unroll
  for (int mf = 0; mf < 2; ++mf) {
#pragma unroll
    for (int nf = 0; nf < 4; ++nf) {
      const int m0 = mbase + w * 32 + mf * 16 + lg * 4;
      const int n  = nf * 16 + lr;
      short4 vv = *reinterpret_cast<const short4*>(&VTh[(size_t)n * SEQ + m0]);
      float4 fc = *reinterpret_cast<const float4*>(&Fh[m0]);
      float o0 = bf2f((u16)vv.x) + fc.x * acc[mf][nf][0];
      float o1 = bf2f((u16)vv.y) + fc.y * acc[mf][nf][1];
      float o2 = bf2f((u16)vv.z) + fc.z * acc[mf][nf][2];
      float o3 = bf2f((u16)vv.w) + fc.w * acc[mf][nf][3];
      *reinterpret_cast<uint32_t*>(&Ro8[(size_t)n * SEQ + m0]) = pk4_fp8(o0, o1, o2, o3);
      if (writeAttn) {
        size_t base = ((size_t)b * SEQ + m0) * DM + hh * DH + n;
        attn[base]          = f2bf(o0);
        attn[base + DM]     = f2bf(o1);
        attn[base + 2 * DM] = f2bf(o2);
        attn[base + 3 * DM] = f2bf(o3);
      }
    }
  }
}

extern "C" void kernel_launch(void* const* d_in, const int* in_sizes, int n_in,
                              void* d_out, int out_size, void* d_ws, size_t ws_size,
                              hipStream_t stream) {
  const float* q_f = (const float*)d_in[0];
  const float* k_f = (const float*)d_in[1];
  const float* v_f = (const float*)d_in[2];
  const float* Wq  = (const float*)d_in[3];
  const float* Wk  = (const float*)d_in[4];
  const float* Wv  = (const float*)d_in[5];
  const float* Wo  = (const float*)d_in[6];
  const float* bo  = (const float*)d_in[7];

  char* ws = (char*)d_ws;
  size_t o = 0;
  auto take = [&](size_t b) { size_t p = o; o += (b + 255) & ~(size_t)255; return p; };
  const size_t SZ_ACT = (size_t)MR * DM * 2;        // 8 MB
  const size_t SZ_W   = (size_t)DM * DM * 2;        // 0.5 MB
  const size_t SZ_R8  = (size_t)BHN * DH * SEQ;     // 4 MB
  size_t o_qbf = take(SZ_ACT);                      // later: attn
  size_t o_kbf = take(SZ_ACT);                      // later: r8A + r8B
  size_t o_vbf = take(SZ_ACT);
  size_t o_wq = take(SZ_W), o_wk = take(SZ_W), o_wv = take(SZ_W), o_wo = take(SZ_W);
  size_t o_Qh = take(SZ_ACT);
  size_t o_Kh = take(SZ_ACT);
  size_t o_VT = take(SZ_ACT);
  size_t o_V8 = take(SZ_R8);
  size_t o_Ds = take((size_t)BHN * SEQ * 4);
  size_t o_Fc = take((size_t)BHN * SEQ * 4);
  size_t o_E  = take((size_t)BHN * SEQ * SEQ);      // 128 MB fp8
  if (ws_size < o) {  // workspace insufficient -> unambiguous diagnostic
    k_diag<<<dim3((out_size + 255) / 256), dim3(256), 0, stream>>>((float*)d_out, out_size);
    return;
  }
  u16* q_bf = (u16*)(ws + o_qbf);
  u16* k_bf = (u16*)(ws + o_kbf);
  u16* v_bf = (u16*)(ws + o_vbf);
  u16* wq_bf = (u16*)(ws + o_wq); u16* wk_bf = (u16*)(ws + o_wk);
  u16* wv_bf = (u16*)(ws + o_wv); u16* wo_bf = (u16*)(ws + o_wo);
  u16* Qh = (u16*)(ws + o_Qh);
  u16* Kh = (u16*)(ws + o_Kh);
  u16* VT = (u16*)(ws + o_VT);
  u8*  V8 = (u8*)(ws + o_V8);
  float* Dsum = (float*)(ws + o_Ds);
  float* Fac  = (float*)(ws + o_Fc);
  u8* E = (u8*)(ws + o_E);
  // aliases (lifetimes disjoint): attn over q_bf, r8 ping-pong over k_bf
  u16* attn = (u16*)(ws + o_qbf);
  u8* r8A = (u8*)(ws + o_kbf);
  u8* r8B = (u8*)(ws + o_kbf + SZ_R8);

  // 1) fp32 -> bf16 conversions
  {
    int n4 = MR * DM / 4;
    k_cvt<<<dim3((n4 + 255) / 256), dim3(256), 0, stream>>>(q_f, q_bf, n4);
    k_cvt<<<dim3((n4 + 255) / 256), dim3(256), 0, stream>>>(k_f, k_bf, n4);
    k_cvt<<<dim3((n4 + 255) / 256), dim3(256), 0, stream>>>(v_f, v_bf, n4);
    int w4 = DM * DM / 4;
    k_cvt<<<dim3((w4 + 255) / 256), dim3(256), 0, stream>>>(Wq, wq_bf, w4);
    k_cvt<<<dim3((w4 + 255) / 256), dim3(256), 0, stream>>>(Wk, wk_bf, w4);
    k_cvt<<<dim3((w4 + 255) / 256), dim3(256), 0, stream>>>(Wv, wv_bf, w4);
    k_cvt<<<dim3((w4 + 255) / 256), dim3(256), 0, stream>>>(Wo, wo_bf, w4);
  }

  // 2) projections
  dim3 pgrid(DM / 128, MR / 128);
  k_gemm_bt<0><<<pgrid, dim3(256), 0, stream>>>(q_bf, wq_bf, Qh, nullptr, nullptr, DM, DM, DM, DM);
  k_gemm_bt<0><<<pgrid, dim3(256), 0, stream>>>(k_bf, wk_bf, Kh, nullptr, nullptr, DM, DM, DM, DM);
  k_gemm_bt<1><<<pgrid, dim3(256), 0, stream>>>(v_bf, wv_bf, VT, V8, nullptr, DM, DM, DM, DM);

  // 3) scores: E = exp(scale*QK^T) in fp8, Dsum = fp32 row sums
  hipMemsetAsync(Dsum, 0, (size_t)BHN * SEQ * 4, stream);
  k_scores<<<dim3(SEQ / 128, SEQ / 128, BHN), dim3(256), 0, stream>>>(Qh, Kh, E, Dsum);
  k_fac<<<dim3(BHN * SEQ / 256), dim3(256), 0, stream>>>(Dsum, Fac, BHN * SEQ);

  // 4) Horner: r <- V + (beta/D) * E @ r, 10 times (r0 = V); last writes attn
  const u8* rin8 = V8;
  u8* r8bufs[2] = {r8A, r8B};
  for (int it = 0; it < NITER; ++it) {
    u8* ro8 = r8bufs[it & 1];
    k_horner8<<<dim3(SEQ / 128, BHN), dim3(256), 0, stream>>>(
        E, rin8, VT, Fac, ro8, attn, (it == NITER - 1) ? 1 : 0);
    rin8 = ro8;
  }

  // 5) output projection: out = attn @ Wo^T + bo (fp32)
  k_gemm_bt<2><<<pgrid, dim3(256), 0, stream>>>(attn, wo_bf, d_out, nullptr, bo, DM, DM, DM, DM);
}